// Round 7
// baseline (521.538 us; speedup 1.0000x reference)
//
#include <hip/hip_runtime.h>
#include <stdint.h>

#define TPB   512
#define D_DIM 4096
#define EPW   8        // elements per thread = D/TPB
#define NVEC  (EPW/4)  // 2
#define CAP   256      // candidate capacity per list
#define NQ    (CAP/64)
#define KSEL  16
#define THI0  2.5f     // top candidate threshold (true 16th ~3.2)
#define TLO0  0.02f    // bot candidate threshold (true 16th ~0.005)

// ws layout (floats)
#define WS_STDP 0
#define WS_INV  D_DIM
#define WS_SCAL (2*D_DIM)   // [0]=tau [1]=beta_up [2]=gamma [3]=beta_fam [4]=inv_e_norm

struct SMem {
    float markf[D_DIM];                   // 16 KB: per-element gate value (init 1.0)
    unsigned long long lists[2 * CAP];    // 4 KB: [0,CAP)=top, [CAP,2CAP)=bot
    float red[8][2];
    unsigned int cnt[2];
};

__device__ __forceinline__ float fast_rcp(float v)  { return __builtin_amdgcn_rcpf(v); }
__device__ __forceinline__ float fast_exp2(float v) { return __builtin_amdgcn_exp2f(v); }

// gelu(x) = 0.5x(1+tanh(u)) = x * sigmoid(2u), u = c*(x + 0.044715 x^3)
#define GELU_AN (-2.30220819f)   // -2c*log2e
#define GELU_BN (-0.10294331f)   // -2c*0.044715*log2e
#define TWO_LOG2E (2.8853900817779268f)
#define LOG2E     (1.4426950408889634f)

__device__ __forceinline__ float gelu_fast(float x) {
    float x2 = x * x;
    float s  = fmaf(x2, GELU_BN, GELU_AN);
    float nq = x * s;
    float ex = fast_exp2(nq);
    return x * fast_rcp(1.0f + ex);
}

__device__ __forceinline__ float tanh_fast_pm(float y2l) {
    float ex = fast_exp2(y2l);
    float r  = fast_rcp(1.0f + ex);
    return fmaf(-2.0f, r, 1.0f);
}

__device__ __forceinline__ float top_gate(float zz, float beta_up, float kg) {
    float g = fmaf(beta_up, tanh_fast_pm(zz * kg), 1.0f);
    return fminf(fmaxf(g, 0.1f), 8.0f);
}

// ---- ABLATION: pure load -> gelu -> scale -> store (memory+gelu floor) ----
__global__ __launch_bounds__(TPB) void ablate_gelu(
    const float* __restrict__ x, float* __restrict__ out)
{
    const int tid = threadIdx.x;
    const long long base = (long long)blockIdx.x * D_DIM;
    #pragma unroll
    for (int i = 0; i < NVEC; ++i) {
        const int off = (i * TPB + tid) * 4;
        const float4 xv = *(const float4*)(x + base + off);
        float4 ov;
        ov.x = gelu_fast(xv.x) * 0.9999f;
        ov.y = gelu_fast(xv.y) * 0.9999f;
        ov.z = gelu_fast(xv.z) * 0.9999f;
        ov.w = gelu_fast(xv.w) * 0.9999f;
        *(float4*)(out + base + off) = ov;
    }
}

// ---- precompute: per-column stdp/inv + scalars (1 block) ----
__global__ __launch_bounds__(256) void precomp(
    const float* __restrict__ em, const float* __restrict__ eq,
    const float* __restrict__ eo,
    const float* __restrict__ lt, const float* __restrict__ lb,
    const float* __restrict__ lg, const float* __restrict__ lf,
    float* __restrict__ ws)
{
    __shared__ float red[4];
    const int tid = threadIdx.x;
    float e2 = 0.0f;
    for (int i = 0; i < D_DIM / 256; ++i) {
        const int d = i * 256 + tid;
        const float mu  = em[d];
        const float mu2 = __fmul_rn(mu, mu);
        float var = __fsub_rn(eq[d], mu2);
        var = fmaxf(var, 1e-4f);
        const float stdp = __fadd_rn(sqrtf(var), 1e-5f);  // bit-identical to numpy std+EPS
        ws[WS_STDP + d] = stdp;
        ws[WS_INV + d]  = 1.0f / stdp;
        const float e = eo[d];
        e2 = fmaf(e, e, e2);
    }
    #pragma unroll
    for (int off = 32; off; off >>= 1) e2 += __shfl_xor(e2, off);
    if ((tid & 63) == 0) red[tid >> 6] = e2;
    __syncthreads();
    if (tid == 0) {
        const float t  = red[0] + red[1] + red[2] + red[3];
        const float en = sqrtf(t);
        ws[WS_SCAL + 0] = expf(lt[0]);
        ws[WS_SCAL + 1] = log1pf(expf(lb[0]));
        ws[WS_SCAL + 2] = log1pf(expf(lg[0]));
        ws[WS_SCAL + 3] = 1.0f / (1.0f + expf(-lf[0]));
        ws[WS_SCAL + 4] = 1.0f / fmaxf(en, 1e-12f);
    }
}

__global__ __launch_bounds__(TPB) void fused_gelu_gate(
    const float* __restrict__ x,
    const float* __restrict__ ema_mean,
    const float* __restrict__ ema_out,
    const float* __restrict__ ws,
    float* __restrict__ out)
{
    __shared__ SMem sh;
    const int tid = threadIdx.x;
    const int ln  = tid & 63;
    const int wv  = tid >> 6;
    const long long base = (long long)blockIdx.x * D_DIM;

    // ---- init markf (gate=1) + counters ----
    #pragma unroll
    for (int i = 0; i < NVEC; ++i) {
        float4 one; one.x = 1.0f; one.y = 1.0f; one.z = 1.0f; one.w = 1.0f;
        *(float4*)&sh.markf[(i * TPB + tid) * 4] = one;
    }
    if (tid < 2) sh.cnt[tid] = 0u;
    __syncthreads();                                   // B1

    const float tau      = ws[WS_SCAL + 0];
    const float beta_up  = ws[WS_SCAL + 1];
    const float kg       = ws[WS_SCAL + 2] * TWO_LOG2E;  // gamma * 2log2e
    const float beta_fam = ws[WS_SCAL + 3];
    const float inv_en   = ws[WS_SCAL + 4];

    float o_r[EPW];
    float s_o2 = 0.0f, s_dot = 0.0f;

    // ---- pass 1: load, gelu once (kept), fast z (transient), threshold-collect ----
    #pragma unroll
    for (int i = 0; i < NVEC; ++i) {
        const int off = (i * TPB + tid) * 4;
        const float4 xv = *(const float4*)(x + base + off);
        const float4 mv = *(const float4*)(ema_mean + off);
        const float4 iv = *(const float4*)(ws + WS_INV + off);
        const float4 ev = *(const float4*)(ema_out + off);
        const float xs[4] = {xv.x, xv.y, xv.z, xv.w};
        const float ms[4] = {mv.x, mv.y, mv.z, mv.w};
        const float is[4] = {iv.x, iv.y, iv.z, iv.w};
        const float es[4] = {ev.x, ev.y, ev.z, ev.w};
        #pragma unroll
        for (int j = 0; j < 4; ++j) {
            const int e = i * 4 + j;
            const float xx = xs[j];
            const float zz = (xx - ms[j]) * is[j];
            const float og = gelu_fast(xx);
            o_r[e] = og;
            s_o2  = fmaf(og, og, s_o2);
            s_dot = fmaf(og, es[j], s_dot);
            const float az = fabsf(zz);
            if (az >= THI0 || az <= TLO0) {
                const unsigned int d = (unsigned int)(off + j);
                const float stdp = ws[WS_STDP + d];
                const float zp   = __fdiv_rn(__fsub_rn(xx, ms[j]), stdp);
                const unsigned int zb = __float_as_uint(zp);
                const unsigned int pb = zb & 0x7fffffffu;
                const unsigned int sg = zb >> 31;
                // key_lo: [1s:19][~d:12][sign:1] -> |z| desc, then d asc, sign inert
                const unsigned int klo = 0xFFFFE000u | ((~d & 0xFFFu) << 1) | sg;
                if (az >= THI0) {
                    const unsigned int p = atomicAdd(&sh.cnt[0], 1u);
                    if (p < CAP)
                        sh.lists[p] = ((unsigned long long)pb << 32) | klo;
                } else {
                    const unsigned int p = atomicAdd(&sh.cnt[1], 1u);
                    if (p < CAP)
                        sh.lists[CAP + p] = ((unsigned long long)(pb ^ 0x7fffffffu) << 32) | klo;
                }
            }
        }
    }

    // ---- block-reduce sums ----
    #pragma unroll
    for (int off = 32; off; off >>= 1) {
        s_o2  += __shfl_xor(s_o2, off);
        s_dot += __shfl_xor(s_dot, off);
    }
    if (ln == 0) { sh.red[wv][0] = s_o2; sh.red[wv][1] = s_dot; }
    __syncthreads();                                   // B2

    float t_o2 = 0.0f, t_dot = 0.0f;
    #pragma unroll
    for (int w = 0; w < TPB / 64; ++w) { t_o2 += sh.red[w][0]; t_dot += sh.red[w][1]; }

    // ---- fallback (uniform branch; not taken for sane inputs): re-collect ----
    {
        unsigned int cT = sh.cnt[0], cB = sh.cnt[1];
        float thi = THI0, tlo = TLO0;
        int tries = 0;
        while ((cT < (unsigned)KSEL || cT > (unsigned)CAP ||
                cB < (unsigned)KSEL || cB > (unsigned)CAP) && tries < 20) {
            if (cT < (unsigned)KSEL) thi *= 0.5f; else if (cT > (unsigned)CAP) thi *= 1.5f;
            if (cB < (unsigned)KSEL) tlo *= 2.0f; else if (cB > (unsigned)CAP) tlo *= 0.6666f;
            __syncthreads();
            if (tid < 2) sh.cnt[tid] = 0u;
            __syncthreads();
            #pragma unroll
            for (int e = 0; e < EPW; ++e) {
                const unsigned int d = (unsigned int)(((e >> 2) * TPB + tid) * 4 + (e & 3));
                const float xx   = x[base + d];
                const float mu   = ema_mean[d];
                const float stdp = ws[WS_STDP + d];
                const float zp   = __fdiv_rn(__fsub_rn(xx, mu), stdp);
                const float az   = fabsf(zp);
                if (az >= thi || az <= tlo) {
                    const unsigned int zb = __float_as_uint(zp);
                    const unsigned int pb = zb & 0x7fffffffu;
                    const unsigned int sg = zb >> 31;
                    const unsigned int klo = 0xFFFFE000u | ((~d & 0xFFFu) << 1) | sg;
                    if (az >= thi) {
                        const unsigned int p = atomicAdd(&sh.cnt[0], 1u);
                        if (p < CAP)
                            sh.lists[p] = ((unsigned long long)pb << 32) | klo;
                    } else {
                        const unsigned int p = atomicAdd(&sh.cnt[1], 1u);
                        if (p < CAP)
                            sh.lists[CAP + p] = ((unsigned long long)(pb ^ 0x7fffffffu) << 32) | klo;
                    }
                }
            }
            __syncthreads();
            cT = sh.cnt[0]; cB = sh.cnt[1];
            ++tries;
        }
    }

    // ---- resolve top-16 / bot-16 in registers; winners write gate VALUE to markf ----
    if (wv < 2) {
        const int ph = wv;
        unsigned int m = sh.cnt[ph];
        if (m > CAP) m = CAP;
        unsigned long long key[NQ];
        #pragma unroll
        for (int q = 0; q < NQ; ++q) {
            const unsigned int p = (unsigned int)ln + ((unsigned int)q << 6);
            key[q] = (p < m) ? sh.lists[ph * CAP + p] : 0ull;
        }
        #pragma unroll 1
        for (int it = 0; it < KSEL; ++it) {
            unsigned long long k = 0ull;
            #pragma unroll
            for (int q = 0; q < NQ; ++q) k = (key[q] > k) ? key[q] : k;
            #pragma unroll
            for (int off = 32; off; off >>= 1) {
                const unsigned long long o = __shfl_xor(k, off);
                if (o > k) k = o;
            }
            if (ln == 0 && k != 0ull) {
                const unsigned int klo = (unsigned int)(k & 0xffffffffu);
                const unsigned int d   = (~(klo >> 1)) & 0xFFFu;
                if (ph == 0) {
                    const unsigned int pb = (unsigned int)(k >> 32);
                    const float azf = __uint_as_float(pb);
                    const float zw  = (klo & 1u) ? -azf : azf;
                    sh.markf[d] = top_gate(zw, beta_up, kg);
                } else {
                    sh.markf[d] = beta_fam;
                }
            }
            #pragma unroll
            for (int q = 0; q < NQ; ++q) if (key[q] == k) key[q] = 0ull;  // unique keys
        }
    }
    __syncthreads();                                   // B3

    // ---- final: out = o_r * markf * gc (no reload, no branches) ----
    const float on = sqrtf(t_o2);
    float cs = (t_dot * inv_en) / fmaxf(on, 1e-12f);
    cs = fminf(fmaxf(cs, -1.0f), 1.0f);
    const float gc = fast_exp2(-tau * cs * LOG2E);

    #pragma unroll
    for (int i = 0; i < NVEC; ++i) {
        const int off = (i * TPB + tid) * 4;
        const float4 mf = *(const float4*)&sh.markf[off];
        float4 ov;
        ov.x = o_r[i * 4 + 0] * mf.x * gc;
        ov.y = o_r[i * 4 + 1] * mf.y * gc;
        ov.z = o_r[i * 4 + 2] * mf.z * gc;
        ov.w = o_r[i * 4 + 3] * mf.w * gc;
        *(float4*)(out + base + off) = ov;
    }
}

extern "C" void kernel_launch(void* const* d_in, const int* in_sizes, int n_in,
                              void* d_out, int out_size, void* d_ws, size_t ws_size,
                              hipStream_t stream) {
    const float* x  = (const float*)d_in[0];
    const float* em = (const float*)d_in[1];
    const float* eq = (const float*)d_in[2];
    const float* eo = (const float*)d_in[3];
    const float* lt = (const float*)d_in[4];
    const float* lb = (const float*)d_in[5];
    const float* lg = (const float*)d_in[6];
    const float* lf = (const float*)d_in[7];
    float* o  = (float*)d_out;
    float* ws = (float*)d_ws;
    const int rows = in_sizes[0] / D_DIM;
    precomp<<<dim3(1), dim3(256), 0, stream>>>(em, eq, eo, lt, lb, lg, lf, ws);
    // ABLATION: memory+gelu floor; output overwritten by the real kernel below.
    ablate_gelu<<<dim3(rows), dim3(TPB), 0, stream>>>(x, o);
    fused_gelu_gate<<<dim3(rows), dim3(TPB), 0, stream>>>(x, em, eo, ws, o);
}

// Round 8
// 232.497 us; speedup vs baseline: 2.2432x; 2.2432x over previous
//
#include <hip/hip_runtime.h>
#include <stdint.h>

#define TPB   256
#define D_DIM 4096
#define EPW   16       // elements per thread = D/TPB
#define NVEC  (EPW/4)  // 4
#define CAP   256      // candidate capacity per list
#define NQ    (CAP/64)
#define KSEL  16
#define THI0  2.5f     // top candidate threshold (~51/row expected, min 16 needed)
#define TLO0  0.02f    // bot candidate threshold (~65/row expected)

// ws layout (floats)
#define WS_STDP 0
#define WS_INV  D_DIM
#define WS_SCAL (2*D_DIM)   // [0]=tau [1]=beta_up [2]=gamma [3]=beta_fam [4]=inv_e_norm

struct SMem {
    float markf[D_DIM];                   // 16 KB: per-element gate value (init 1.0)
    unsigned long long lists[2 * CAP];    // 4 KB: [0,CAP)=top, [CAP,2CAP)=bot
    float red[4][2];
    unsigned int cnt[2];
};

__device__ __forceinline__ float fast_rcp(float v)  { return __builtin_amdgcn_rcpf(v); }
__device__ __forceinline__ float fast_exp2(float v) { return __builtin_amdgcn_exp2f(v); }

// gelu(x) = 0.5x(1+tanh(u)) = x * sigmoid(2u), u = c*(x + 0.044715 x^3)
#define GELU_AN (-2.30220819f)   // -2c*log2e
#define GELU_BN (-0.10294331f)   // -2c*0.044715*log2e
#define TWO_LOG2E (2.8853900817779268f)
#define LOG2E     (1.4426950408889634f)

__device__ __forceinline__ float gelu_fast(float x) {
    float x2 = x * x;
    float s  = fmaf(x2, GELU_BN, GELU_AN);
    float nq = x * s;
    float ex = fast_exp2(nq);
    return x * fast_rcp(1.0f + ex);
}

__device__ __forceinline__ float tanh_fast_pm(float y2l) {
    float ex = fast_exp2(y2l);
    float r  = fast_rcp(1.0f + ex);
    return fmaf(-2.0f, r, 1.0f);
}

__device__ __forceinline__ float top_gate(float zz, float beta_up, float kg) {
    float g = fmaf(beta_up, tanh_fast_pm(zz * kg), 1.0f);
    return fminf(fmaxf(g, 0.1f), 8.0f);
}

// exact numpy z key: |z|-bits desc, tie -> lowest d; sign in LSB (inert for order)
__device__ __forceinline__ unsigned long long make_key_top(float zp, unsigned int d) {
    const unsigned int zb = __float_as_uint(zp);
    const unsigned int pb = zb & 0x7fffffffu;
    const unsigned int klo = 0xFFFFE000u | ((~d & 0xFFFu) << 1) | (zb >> 31);
    return ((unsigned long long)pb << 32) | klo;
}
__device__ __forceinline__ unsigned long long make_key_bot(float zp, unsigned int d) {
    const unsigned int zb = __float_as_uint(zp);
    const unsigned int pb = (zb & 0x7fffffffu) ^ 0x7fffffffu;
    const unsigned int klo = 0xFFFFE000u | ((~d & 0xFFFu) << 1) | (zb >> 31);
    return ((unsigned long long)pb << 32) | klo;
}

// ---- precompute: per-column stdp/inv + scalars (1 block) ----
__global__ __launch_bounds__(256) void precomp(
    const float* __restrict__ em, const float* __restrict__ eq,
    const float* __restrict__ eo,
    const float* __restrict__ lt, const float* __restrict__ lb,
    const float* __restrict__ lg, const float* __restrict__ lf,
    float* __restrict__ ws)
{
    __shared__ float red[4];
    const int tid = threadIdx.x;
    float e2 = 0.0f;
    for (int i = 0; i < D_DIM / 256; ++i) {
        const int d = i * 256 + tid;
        const float mu  = em[d];
        const float mu2 = __fmul_rn(mu, mu);
        float var = __fsub_rn(eq[d], mu2);
        var = fmaxf(var, 1e-4f);
        const float stdp = __fadd_rn(sqrtf(var), 1e-5f);  // bit-identical to numpy std+EPS
        ws[WS_STDP + d] = stdp;
        ws[WS_INV + d]  = 1.0f / stdp;
        const float e = eo[d];
        e2 = fmaf(e, e, e2);
    }
    #pragma unroll
    for (int off = 32; off; off >>= 1) e2 += __shfl_xor(e2, off);
    if ((tid & 63) == 0) red[tid >> 6] = e2;
    __syncthreads();
    if (tid == 0) {
        const float t  = red[0] + red[1] + red[2] + red[3];
        const float en = sqrtf(t);
        ws[WS_SCAL + 0] = expf(lt[0]);
        ws[WS_SCAL + 1] = log1pf(expf(lb[0]));
        ws[WS_SCAL + 2] = log1pf(expf(lg[0]));
        ws[WS_SCAL + 3] = 1.0f / (1.0f + expf(-lf[0]));
        ws[WS_SCAL + 4] = 1.0f / fmaxf(en, 1e-12f);
    }
}

__global__ __launch_bounds__(TPB, 4) void fused_gelu_gate(
    const float* __restrict__ x,
    const float* __restrict__ ema_mean,
    const float* __restrict__ ema_out,
    const float* __restrict__ ws,
    float* __restrict__ out)
{
    __shared__ SMem sh;
    const int tid = threadIdx.x;
    const int ln  = tid & 63;
    const int wv  = tid >> 6;
    const long long base = (long long)blockIdx.x * D_DIM;

    // ---- init markf (gate=1) + counters ----
    #pragma unroll
    for (int i = 0; i < NVEC; ++i) {
        float4 one; one.x = 1.0f; one.y = 1.0f; one.z = 1.0f; one.w = 1.0f;
        *(float4*)&sh.markf[(i * TPB + tid) * 4] = one;
    }
    if (tid < 2) sh.cnt[tid] = 0u;
    __syncthreads();                                   // B1

    const float tau      = ws[WS_SCAL + 0];
    const float beta_up  = ws[WS_SCAL + 1];
    const float kg       = ws[WS_SCAL + 2] * TWO_LOG2E;  // gamma * 2log2e
    const float beta_fam = ws[WS_SCAL + 3];
    const float inv_en   = ws[WS_SCAL + 4];

    float x_r[EPW];
    float s_o2 = 0.0f, s_dot = 0.0f;
    unsigned int maskT = 0u, maskB = 0u;   // per-thread candidate bitmasks

    // ---- pass 1: load, gelu (sums), fast z -> branchless candidate masks ----
    #pragma unroll
    for (int i = 0; i < NVEC; ++i) {
        const int off = (i * TPB + tid) * 4;
        const float4 xv = *(const float4*)(x + base + off);
        const float4 mv = *(const float4*)(ema_mean + off);
        const float4 iv = *(const float4*)(ws + WS_INV + off);
        const float4 ev = *(const float4*)(ema_out + off);
        const float xs[4] = {xv.x, xv.y, xv.z, xv.w};
        const float ms[4] = {mv.x, mv.y, mv.z, mv.w};
        const float is[4] = {iv.x, iv.y, iv.z, iv.w};
        const float es[4] = {ev.x, ev.y, ev.z, ev.w};
        #pragma unroll
        for (int j = 0; j < 4; ++j) {
            const int e = i * 4 + j;
            const float xx = xs[j];
            const float zz = (xx - ms[j]) * is[j];
            const float og = gelu_fast(xx);
            x_r[e] = xx;
            s_o2  = fmaf(og, og, s_o2);
            s_dot = fmaf(og, es[j], s_dot);
            const float az = fabsf(zz);
            maskT |= (az >= THI0) ? (1u << e) : 0u;
            maskB |= (az <= TLO0) ? (1u << e) : 0u;
        }
    }

    // ---- deferred candidate collect (rare; ~4 iterations per wave) ----
    {
        unsigned int mT = maskT;
        while (mT) {
            const int e = __ffs(mT) - 1; mT &= mT - 1u;
            const unsigned int d = (unsigned int)(((e >> 2) * TPB + tid) * 4 + (e & 3));
            const float mu   = ema_mean[d];
            const float stdp = ws[WS_STDP + d];
            const float zp   = __fdiv_rn(__fsub_rn(x_r[e], mu), stdp);
            const unsigned int p = atomicAdd(&sh.cnt[0], 1u);
            if (p < CAP) sh.lists[p] = make_key_top(zp, d);
        }
        unsigned int mB = maskB;
        while (mB) {
            const int e = __ffs(mB) - 1; mB &= mB - 1u;
            const unsigned int d = (unsigned int)(((e >> 2) * TPB + tid) * 4 + (e & 3));
            const float mu   = ema_mean[d];
            const float stdp = ws[WS_STDP + d];
            const float zp   = __fdiv_rn(__fsub_rn(x_r[e], mu), stdp);
            const unsigned int p = atomicAdd(&sh.cnt[1], 1u);
            if (p < CAP) sh.lists[CAP + p] = make_key_bot(zp, d);
        }
    }

    // ---- block-reduce sums ----
    #pragma unroll
    for (int off = 32; off; off >>= 1) {
        s_o2  += __shfl_xor(s_o2, off);
        s_dot += __shfl_xor(s_dot, off);
    }
    if (ln == 0) { sh.red[wv][0] = s_o2; sh.red[wv][1] = s_dot; }
    __syncthreads();                                   // B2

    float t_o2 = 0.0f, t_dot = 0.0f;
    #pragma unroll
    for (int w = 0; w < TPB / 64; ++w) { t_o2 += sh.red[w][0]; t_dot += sh.red[w][1]; }

    // ---- fallback (uniform branch; never taken for sane inputs) ----
    {
        unsigned int cT = sh.cnt[0], cB = sh.cnt[1];
        float thi = THI0, tlo = TLO0;
        int tries = 0;
        while ((cT < (unsigned)KSEL || cT > (unsigned)CAP ||
                cB < (unsigned)KSEL || cB > (unsigned)CAP) && tries < 20) {
            if (cT < (unsigned)KSEL) thi *= 0.5f; else if (cT > (unsigned)CAP) thi *= 1.5f;
            if (cB < (unsigned)KSEL) tlo *= 2.0f; else if (cB > (unsigned)CAP) tlo *= 0.6666f;
            __syncthreads();
            if (tid < 2) sh.cnt[tid] = 0u;
            __syncthreads();
            for (int e = 0; e < EPW; ++e) {
                const unsigned int d = (unsigned int)(((e >> 2) * TPB + tid) * 4 + (e & 3));
                const float mu   = ema_mean[d];
                const float stdp = ws[WS_STDP + d];
                const float zp   = __fdiv_rn(__fsub_rn(x_r[e], mu), stdp);
                const float az   = fabsf(zp);
                if (az >= thi) {
                    const unsigned int p = atomicAdd(&sh.cnt[0], 1u);
                    if (p < CAP) sh.lists[p] = make_key_top(zp, d);
                } else if (az <= tlo) {
                    const unsigned int p = atomicAdd(&sh.cnt[1], 1u);
                    if (p < CAP) sh.lists[CAP + p] = make_key_bot(zp, d);
                }
            }
            __syncthreads();
            cT = sh.cnt[0]; cB = sh.cnt[1];
            ++tries;
        }
    }

    // ---- resolve top-16 / bot-16 in registers; winners write gate VALUE to markf ----
    if (wv < 2) {
        const int ph = wv;
        unsigned int m = sh.cnt[ph];
        if (m > CAP) m = CAP;
        unsigned long long key[NQ];
        #pragma unroll
        for (int q = 0; q < NQ; ++q) {
            const unsigned int p = (unsigned int)ln + ((unsigned int)q << 6);
            key[q] = (p < m) ? sh.lists[ph * CAP + p] : 0ull;
        }
        #pragma unroll 1
        for (int it = 0; it < KSEL; ++it) {
            unsigned long long k = 0ull;
            #pragma unroll
            for (int q = 0; q < NQ; ++q) k = (key[q] > k) ? key[q] : k;
            #pragma unroll
            for (int off = 32; off; off >>= 1) {
                const unsigned long long o = __shfl_xor(k, off);
                if (o > k) k = o;
            }
            if (ln == 0 && k != 0ull) {
                const unsigned int klo = (unsigned int)(k & 0xffffffffu);
                const unsigned int d   = (~(klo >> 1)) & 0xFFFu;
                if (ph == 0) {
                    const unsigned int pb = (unsigned int)(k >> 32);
                    const float azf = __uint_as_float(pb);
                    const float zw  = (klo & 1u) ? -azf : azf;
                    sh.markf[d] = top_gate(zw, beta_up, kg);
                } else {
                    sh.markf[d] = beta_fam;
                }
            }
            #pragma unroll
            for (int q = 0; q < NQ; ++q) if (key[q] == k) key[q] = 0ull;  // unique keys
        }
    }
    __syncthreads();                                   // B3

    // ---- final: out = gelu(x_r) * markf * gc ----
    const float on = sqrtf(t_o2);
    float cs = (t_dot * inv_en) / fmaxf(on, 1e-12f);
    cs = fminf(fmaxf(cs, -1.0f), 1.0f);
    const float gc = fast_exp2(-tau * cs * LOG2E);

    #pragma unroll
    for (int i = 0; i < NVEC; ++i) {
        const int off = (i * TPB + tid) * 4;
        const float4 mf = *(const float4*)&sh.markf[off];
        float4 ov;
        ov.x = gelu_fast(x_r[i * 4 + 0]) * mf.x * gc;
        ov.y = gelu_fast(x_r[i * 4 + 1]) * mf.y * gc;
        ov.z = gelu_fast(x_r[i * 4 + 2]) * mf.z * gc;
        ov.w = gelu_fast(x_r[i * 4 + 3]) * mf.w * gc;
        *(float4*)(out + base + off) = ov;
    }
}

extern "C" void kernel_launch(void* const* d_in, const int* in_sizes, int n_in,
                              void* d_out, int out_size, void* d_ws, size_t ws_size,
                              hipStream_t stream) {
    const float* x  = (const float*)d_in[0];
    const float* em = (const float*)d_in[1];
    const float* eq = (const float*)d_in[2];
    const float* eo = (const float*)d_in[3];
    const float* lt = (const float*)d_in[4];
    const float* lb = (const float*)d_in[5];
    const float* lg = (const float*)d_in[6];
    const float* lf = (const float*)d_in[7];
    float* o  = (float*)d_out;
    float* ws = (float*)d_ws;
    const int rows = in_sizes[0] / D_DIM;
    precomp<<<dim3(1), dim3(256), 0, stream>>>(em, eq, eo, lt, lb, lg, lf, ws);
    fused_gelu_gate<<<dim3(rows), dim3(TPB), 0, stream>>>(x, em, eo, ws, o);
}

// Round 9
// 220.574 us; speedup vs baseline: 2.3645x; 1.0541x over previous
//
#include <hip/hip_runtime.h>
#include <stdint.h>

#define TPB   256
#define D_DIM 4096
#define EPW   16       // elements per thread = D/TPB
#define NVEC  (EPW/4)  // 4
#define CAP   256      // candidate capacity per list
#define NQ    (CAP/64)
#define KSEL  16
#define THI0  2.5f     // top candidate threshold (true 16th ~3.2)
#define TLO0  0.02f    // bot candidate threshold (true 16th ~0.005)

// ws layout: [0,D) stdp (float) | [D,2D) packed bf16 (mu<<16|inv) (uint) | [2D..] scalars
#define WS_STDP 0
#define WS_MI   D_DIM
#define WS_SCAL (2*D_DIM)   // [0]=tau [1]=beta_up [2]=gamma [3]=beta_fam [4]=inv_e_norm

struct SMem {
    float markf[D_DIM];                   // 16 KB, TRANSPOSED: [(d&3)*1024 + (d>>2)]
    unsigned long long lists[2 * CAP];    // 4 KB: [0,CAP)=top, [CAP,2CAP)=bot
    float red[4][2];
    unsigned int cnt[2];
};

__device__ __forceinline__ float fast_rcp(float v)  { return __builtin_amdgcn_rcpf(v); }
__device__ __forceinline__ float fast_exp2(float v) { return __builtin_amdgcn_exp2f(v); }

// gelu(x) = 0.5x(1+tanh(u)) = x * sigmoid(2u), u = c*(x + 0.044715 x^3)
#define GELU_AN (-2.30220819f)   // -2c*log2e
#define GELU_BN (-0.10294331f)   // -2c*0.044715*log2e
#define TWO_LOG2E (2.8853900817779268f)
#define LOG2E     (1.4426950408889634f)

__device__ __forceinline__ float gelu_fast(float x) {
    float x2 = x * x;
    float s  = fmaf(x2, GELU_BN, GELU_AN);
    float nq = x * s;
    float ex = fast_exp2(nq);
    return x * fast_rcp(1.0f + ex);
}

__device__ __forceinline__ float tanh_fast_pm(float y2l) {
    float ex = fast_exp2(y2l);
    float r  = fast_rcp(1.0f + ex);
    return fmaf(-2.0f, r, 1.0f);
}

__device__ __forceinline__ float top_gate(float zz, float beta_up, float kg) {
    float g = fmaf(beta_up, tanh_fast_pm(zz * kg), 1.0f);
    return fminf(fmaxf(g, 0.1f), 8.0f);
}

// exact numpy z key: |z|-bits desc, tie -> lowest d; sign in LSB (inert for order)
__device__ __forceinline__ unsigned long long make_key_top(float zp, unsigned int d) {
    const unsigned int zb = __float_as_uint(zp);
    const unsigned int pb = zb & 0x7fffffffu;
    const unsigned int klo = 0xFFFFE000u | ((~d & 0xFFFu) << 1) | (zb >> 31);
    return ((unsigned long long)pb << 32) | klo;
}
__device__ __forceinline__ unsigned long long make_key_bot(float zp, unsigned int d) {
    const unsigned int zb = __float_as_uint(zp);
    const unsigned int pb = (zb & 0x7fffffffu) ^ 0x7fffffffu;
    const unsigned int klo = 0xFFFFE000u | ((~d & 0xFFFu) << 1) | (zb >> 31);
    return ((unsigned long long)pb << 32) | klo;
}

__device__ __forceinline__ unsigned int bf16_hi(float v) {
    unsigned int u = __float_as_uint(v);
    u = (u + 0x7FFFu + ((u >> 16) & 1u)) >> 16;   // round-to-nearest-even bf16
    return u & 0xFFFFu;
}

// ---- precompute: per-column stdp + packed bf16 (mu,inv) + scalars (1 block) ----
__global__ __launch_bounds__(256) void precomp(
    const float* __restrict__ em, const float* __restrict__ eq,
    const float* __restrict__ eo,
    const float* __restrict__ lt, const float* __restrict__ lb,
    const float* __restrict__ lg, const float* __restrict__ lf,
    float* __restrict__ ws)
{
    __shared__ float red[4];
    const int tid = threadIdx.x;
    unsigned int* wsu = (unsigned int*)ws;
    float e2 = 0.0f;
    for (int i = 0; i < D_DIM / 256; ++i) {
        const int d = i * 256 + tid;
        const float mu  = em[d];
        const float mu2 = __fmul_rn(mu, mu);
        float var = __fsub_rn(eq[d], mu2);
        var = fmaxf(var, 1e-4f);
        const float stdp = __fadd_rn(sqrtf(var), 1e-5f);  // bit-identical to numpy std+EPS
        ws[WS_STDP + d] = stdp;
        const float invv = 1.0f / stdp;
        wsu[WS_MI + d] = (bf16_hi(mu) << 16) | bf16_hi(invv);
        const float e = eo[d];
        e2 = fmaf(e, e, e2);
    }
    #pragma unroll
    for (int off = 32; off; off >>= 1) e2 += __shfl_xor(e2, off);
    if ((tid & 63) == 0) red[tid >> 6] = e2;
    __syncthreads();
    if (tid == 0) {
        const float t  = red[0] + red[1] + red[2] + red[3];
        const float en = sqrtf(t);
        ws[WS_SCAL + 0] = expf(lt[0]);
        ws[WS_SCAL + 1] = log1pf(expf(lb[0]));
        ws[WS_SCAL + 2] = log1pf(expf(lg[0]));
        ws[WS_SCAL + 3] = 1.0f / (1.0f + expf(-lf[0]));
        ws[WS_SCAL + 4] = 1.0f / fmaxf(en, 1e-12f);
    }
}

__global__ __launch_bounds__(TPB, 4) void fused_gelu_gate(
    const float* __restrict__ x,
    const float* __restrict__ ema_mean,
    const float* __restrict__ ema_out,
    const float* __restrict__ ws,
    float* __restrict__ out)
{
    __shared__ SMem sh;
    const int tid = threadIdx.x;
    const int ln  = tid & 63;
    const int wv  = tid >> 6;
    const long long base = (long long)blockIdx.x * D_DIM;

    // ---- init markf (gate=1) + counters ----
    #pragma unroll
    for (int i = 0; i < NVEC; ++i) {
        float4 one; one.x = 1.0f; one.y = 1.0f; one.z = 1.0f; one.w = 1.0f;
        *(float4*)&sh.markf[(i * TPB + tid) * 4] = one;
    }
    if (tid < 2) sh.cnt[tid] = 0u;
    __syncthreads();                                   // B1

    const float tau      = ws[WS_SCAL + 0];
    const float beta_up  = ws[WS_SCAL + 1];
    const float kg       = ws[WS_SCAL + 2] * TWO_LOG2E;  // gamma * 2log2e
    const float beta_fam = ws[WS_SCAL + 3];
    const float inv_en   = ws[WS_SCAL + 4];
    const unsigned int* mip = (const unsigned int*)ws + WS_MI;

    float o_r[EPW];
    float s_o2 = 0.0f, s_dot = 0.0f;
    unsigned int maskT = 0u, maskB = 0u;   // per-thread candidate bitmasks

    // ---- pass 1: 3 streams (x, packed bf16 mu|inv, e); gelu ONCE; branchless masks ----
    #pragma unroll
    for (int i = 0; i < NVEC; ++i) {
        const int off = (i * TPB + tid) * 4;
        const float4 xv = *(const float4*)(x + base + off);
        const uint4  mv = *(const uint4*)(mip + off);
        const float4 ev = *(const float4*)(ema_out + off);
        const float xs[4] = {xv.x, xv.y, xv.z, xv.w};
        const unsigned int mis[4] = {mv.x, mv.y, mv.z, mv.w};
        const float es[4] = {ev.x, ev.y, ev.z, ev.w};
        #pragma unroll
        for (int j = 0; j < 4; ++j) {
            const int e = i * 4 + j;
            const float xx = xs[j];
            const float mu = __uint_as_float(mis[j] & 0xFFFF0000u);
            const float iv = __uint_as_float(mis[j] << 16);
            const float zz = (xx - mu) * iv;
            const float og = gelu_fast(xx);
            o_r[e] = og;
            s_o2  = fmaf(og, og, s_o2);
            s_dot = fmaf(og, es[j], s_dot);
            const float az = fabsf(zz);
            maskT |= (az >= THI0) ? (1u << e) : 0u;
            maskB |= (az <= TLO0) ? (1u << e) : 0u;
        }
    }

    // ---- deferred candidate collect (rare): exact z via x reload (L2-hot) ----
    {
        unsigned int mT = maskT;
        while (mT) {
            const int e = __ffs(mT) - 1; mT &= mT - 1u;
            const unsigned int d = (unsigned int)(((e >> 2) * TPB + tid) * 4 + (e & 3));
            const float xx   = x[base + d];
            const float mu   = ema_mean[d];
            const float stdp = ws[WS_STDP + d];
            const float zp   = __fdiv_rn(__fsub_rn(xx, mu), stdp);
            const unsigned int p = atomicAdd(&sh.cnt[0], 1u);
            if (p < CAP) sh.lists[p] = make_key_top(zp, d);
        }
        unsigned int mB = maskB;
        while (mB) {
            const int e = __ffs(mB) - 1; mB &= mB - 1u;
            const unsigned int d = (unsigned int)(((e >> 2) * TPB + tid) * 4 + (e & 3));
            const float xx   = x[base + d];
            const float mu   = ema_mean[d];
            const float stdp = ws[WS_STDP + d];
            const float zp   = __fdiv_rn(__fsub_rn(xx, mu), stdp);
            const unsigned int p = atomicAdd(&sh.cnt[1], 1u);
            if (p < CAP) sh.lists[CAP + p] = make_key_bot(zp, d);
        }
    }

    // ---- block-reduce sums ----
    #pragma unroll
    for (int off = 32; off; off >>= 1) {
        s_o2  += __shfl_xor(s_o2, off);
        s_dot += __shfl_xor(s_dot, off);
    }
    if (ln == 0) { sh.red[wv][0] = s_o2; sh.red[wv][1] = s_dot; }
    __syncthreads();                                   // B2

    float t_o2 = 0.0f, t_dot = 0.0f;
    #pragma unroll
    for (int w = 0; w < TPB / 64; ++w) { t_o2 += sh.red[w][0]; t_dot += sh.red[w][1]; }

    // ---- fallback (uniform branch; never taken for sane inputs) ----
    {
        unsigned int cT = sh.cnt[0], cB = sh.cnt[1];
        float thi = THI0, tlo = TLO0;
        int tries = 0;
        while ((cT < (unsigned)KSEL || cT > (unsigned)CAP ||
                cB < (unsigned)KSEL || cB > (unsigned)CAP) && tries < 20) {
            if (cT < (unsigned)KSEL) thi *= 0.5f; else if (cT > (unsigned)CAP) thi *= 1.5f;
            if (cB < (unsigned)KSEL) tlo *= 2.0f; else if (cB > (unsigned)CAP) tlo *= 0.6666f;
            __syncthreads();
            if (tid < 2) sh.cnt[tid] = 0u;
            __syncthreads();
            for (int e = 0; e < EPW; ++e) {
                const unsigned int d = (unsigned int)(((e >> 2) * TPB + tid) * 4 + (e & 3));
                const float xx   = x[base + d];
                const float mu   = ema_mean[d];
                const float stdp = ws[WS_STDP + d];
                const float zp   = __fdiv_rn(__fsub_rn(xx, mu), stdp);
                const float az   = fabsf(zp);
                if (az >= thi) {
                    const unsigned int p = atomicAdd(&sh.cnt[0], 1u);
                    if (p < CAP) sh.lists[p] = make_key_top(zp, d);
                } else if (az <= tlo) {
                    const unsigned int p = atomicAdd(&sh.cnt[1], 1u);
                    if (p < CAP) sh.lists[CAP + p] = make_key_bot(zp, d);
                }
            }
            __syncthreads();
            cT = sh.cnt[0]; cB = sh.cnt[1];
            ++tries;
        }
    }

    // ---- resolve top-16 / bot-16 in registers; winners write gate VALUE to markf ----
    if (wv < 2) {
        const int ph = wv;
        unsigned int m = sh.cnt[ph];
        if (m > CAP) m = CAP;
        unsigned long long key[NQ];
        #pragma unroll
        for (int q = 0; q < NQ; ++q) {
            const unsigned int p = (unsigned int)ln + ((unsigned int)q << 6);
            key[q] = (p < m) ? sh.lists[ph * CAP + p] : 0ull;
        }
        #pragma unroll 1
        for (int it = 0; it < KSEL; ++it) {
            unsigned long long k = 0ull;
            #pragma unroll
            for (int q = 0; q < NQ; ++q) k = (key[q] > k) ? key[q] : k;
            #pragma unroll
            for (int off = 32; off; off >>= 1) {
                const unsigned long long o = __shfl_xor(k, off);
                if (o > k) k = o;
            }
            if (ln == 0 && k != 0ull) {
                const unsigned int klo = (unsigned int)(k & 0xffffffffu);
                const unsigned int d   = (~(klo >> 1)) & 0xFFFu;
                const unsigned int ti  = (d & 3u) * (D_DIM / 4) + (d >> 2);
                if (ph == 0) {
                    const unsigned int pb = (unsigned int)(k >> 32);
                    const float azf = __uint_as_float(pb);
                    const float zw  = (klo & 1u) ? -azf : azf;
                    sh.markf[ti] = top_gate(zw, beta_up, kg);
                } else {
                    sh.markf[ti] = beta_fam;
                }
            }
            #pragma unroll
            for (int q = 0; q < NQ; ++q) if (key[q] == k) key[q] = 0ull;  // unique keys
        }
    }
    __syncthreads();                                   // B3

    // ---- final: out = o_r * markf * gc (transposed, conflict-free LDS reads) ----
    const float on = sqrtf(t_o2);
    float cs = (t_dot * inv_en) / fmaxf(on, 1e-12f);
    cs = fminf(fmaxf(cs, -1.0f), 1.0f);
    const float gc = fast_exp2(-tau * cs * LOG2E);

    #pragma unroll
    for (int i = 0; i < NVEC; ++i) {
        const int idx = i * TPB + tid;                 // = d>>2 for this 4-group
        const float m0 = sh.markf[0 * (D_DIM / 4) + idx];
        const float m1 = sh.markf[1 * (D_DIM / 4) + idx];
        const float m2 = sh.markf[2 * (D_DIM / 4) + idx];
        const float m3 = sh.markf[3 * (D_DIM / 4) + idx];
        float4 ov;
        ov.x = o_r[i * 4 + 0] * m0 * gc;
        ov.y = o_r[i * 4 + 1] * m1 * gc;
        ov.z = o_r[i * 4 + 2] * m2 * gc;
        ov.w = o_r[i * 4 + 3] * m3 * gc;
        *(float4*)(out + base + (long long)idx * 4) = ov;
    }
}

extern "C" void kernel_launch(void* const* d_in, const int* in_sizes, int n_in,
                              void* d_out, int out_size, void* d_ws, size_t ws_size,
                              hipStream_t stream) {
    const float* x  = (const float*)d_in[0];
    const float* em = (const float*)d_in[1];
    const float* eq = (const float*)d_in[2];
    const float* eo = (const float*)d_in[3];
    const float* lt = (const float*)d_in[4];
    const float* lb = (const float*)d_in[5];
    const float* lg = (const float*)d_in[6];
    const float* lf = (const float*)d_in[7];
    float* o  = (float*)d_out;
    float* ws = (float*)d_ws;
    const int rows = in_sizes[0] / D_DIM;
    precomp<<<dim3(1), dim3(256), 0, stream>>>(em, eq, eo, lt, lb, lg, lf, ws);
    fused_gelu_gate<<<dim3(rows), dim3(TPB), 0, stream>>>(x, em, eo, ws, o);
}